// Round 1
// baseline (3594.337 us; speedup 1.0000x reference)
//
#include <hip/hip_runtime.h>
#include <hip/hip_fp16.h>

// TanhFixedPointLayer: z_{k+1} = tanh(z_k @ W^T + x), z0 = 0, 50 iterations.
// Fused persistent-tile: block owns 64 rows; z double-buffered in LDS (f16,
// frag-packed, 2x64KB); x and accumulators in registers; W pre-packed into
// MFMA A-frag order and streamed from L2 every iteration.
// This revision (latency-bound fixes):
//  - nontemporal x loads / out stores so the streaming traffic does not evict
//    the 512KB Wpk working set from per-XCD L2 (FETCH showed 33% W miss).
//  - depth-4 rolling A-frag prefetch with modular index (ks+4)&15: the W
//    address stream is iteration-independent, so the prefetch runs
//    continuously ACROSS the barrier -> no per-iteration cold start, ~3
//    k-steps (~470 cyc) of latency cover. Uses free VGPR headroom (we are
//    pinned at 2 waves/SIMD by acc+xr anyway; next cliff is 256).
//  - z double-buffer -> ONE barrier per iteration; epilogue VALU of fast
//    waves overlaps MFMA of slow waves.
//  - acc initialized to x (MFMA C-in) instead of 0: epilogue add deleted.

#define DDIM  512
#define MTILE 64
#define NITER 50     // z1 = tanh(x) counts as iteration 1; 49 MFMA iterations

typedef _Float16 half8  __attribute__((ext_vector_type(8)));
typedef _Float16 half4v __attribute__((ext_vector_type(4)));
typedef float    float4v __attribute__((ext_vector_type(4)));

__device__ __forceinline__ float fast_tanh(float t) {
    // tanh(t) = 1 - 2/(exp(2t)+1); exp(2t) = 2^(t*2*log2(e)); exact +-1 at sat.
    float e = __builtin_amdgcn_exp2f(t * 2.8853900817779268f);
    return 1.0f - 2.0f * __builtin_amdgcn_rcpf(e + 1.0f);
}

// z LDS layout = frag-packed: element (m,k) at
//   ((k>>5)*4 + (m>>4))*512 + ((m&15) + 16*((k>>3)&3))*8 + (k&7)
// so B-frag (mf,ks) for lane L is the 16B chunk at ((ks*4+mf)*64 + L)*8.
__device__ __forceinline__ int zaddr(int m, int k) {
    return (((k >> 5) * 4 + (m >> 4)) << 9) + (((m & 15) + (((k >> 3) & 3) << 4)) << 3) + (k & 7);
}

// ---- prep: pack W (fp32 [512][512]) into f16 MFMA A-frag order.
// Frag (ks, nf) block = 64 lanes x 16B: lane L holds
//   W[nf*16 + (L&15)][ks*32 + (L>>4)*8 + j], j=0..7
__global__ void wpack_kernel(const float* __restrict__ W, _Float16* __restrict__ Wpk) {
    int gid  = blockIdx.x * blockDim.x + threadIdx.x;   // 0..32767
    int ks   = gid >> 11;
    int nf   = (gid >> 6) & 31;
    int lane = gid & 63;
    int row  = nf * 16 + (lane & 15);
    int col  = ks * 32 + (lane >> 4) * 8;
    const float* src = W + row * DDIM + col;
    half8 h;
#pragma unroll
    for (int j = 0; j < 8; ++j) h[j] = (_Float16)src[j];
    *(half8*)(Wpk + (size_t)gid * 8) = h;
}

__global__ __launch_bounds__(512, 2)
void fixpoint_kernel(const float* __restrict__ x,
                     const _Float16* __restrict__ Wpk,
                     float* __restrict__ out) {
    __shared__ __align__(16) _Float16 zsh[2][MTILE * DDIM];   // 2 x 64 KB

    const int tid  = threadIdx.x;
    const int lane = tid & 63;
    const int wid  = tid >> 6;          // 0..7, each wave owns 64 n-columns
    const int l15  = lane & 15;
    const int quad = lane >> 4;
    const int nf0  = wid * 4;           // first of this wave's 4 n-frags

    const int row_blk = blockIdx.x * MTILE;
    // A-frag (ks, nf0+f) for this lane: Wv[ks*2048 + f*64]
    const half8* Wv = (const half8*)Wpk + nf0 * 64 + lane;

    // ---- A prefetch for ks=0..3, issued before anything else (z-independent)
    half8 A0[4], A1[4], A2[4], A3[4];
#pragma unroll
    for (int f = 0; f < 4; ++f) A0[f] = Wv[f * 64];
#pragma unroll
    for (int f = 0; f < 4; ++f) A1[f] = Wv[2048 + f * 64];
#pragma unroll
    for (int f = 0; f < 4; ++f) A2[f] = Wv[4096 + f * 64];
#pragma unroll
    for (int f = 0; f < 4; ++f) A3[f] = Wv[6144 + f * 64];

    // ---- x in registers at this lane's C/D slots (nontemporal: keep W in L2)
    // xr[f][mf][r] = x[mf*16+l15][(nf0+f)*16 + quad*4 + r]
    float4v xr[4][4];
#pragma unroll
    for (int f = 0; f < 4; ++f) {
        int n = (nf0 + f) * 16 + quad * 4;
#pragma unroll
        for (int mf = 0; mf < 4; ++mf) {
            const float4v* xp = (const float4v*)(x + (size_t)(row_blk + mf * 16 + l15) * DDIM + n);
            xr[f][mf] = __builtin_nontemporal_load(xp);
        }
    }

    // ---- z1 = tanh(x) -> zsh[0] (b64 contiguous writes)
#pragma unroll
    for (int f = 0; f < 4; ++f) {
        int n = (nf0 + f) * 16 + quad * 4;
#pragma unroll
        for (int mf = 0; mf < 4; ++mf) {
            int m = mf * 16 + l15;
            half4v h;
#pragma unroll
            for (int j = 0; j < 4; ++j) h[j] = (_Float16)fast_tanh(xr[f][mf][j]);
            *(half4v*)(&zsh[0][zaddr(m, n)]) = h;
        }
    }
    __syncthreads();

    int p = 0;
    for (int it = 0; it < NITER - 1; ++it) {
        const _Float16* zr = &zsh[p][0];

        // B-frag double buffer (depth 2; LDS latency ~120cy < 1 ks-step)
        half8 B0[4], B1[4];
#pragma unroll
        for (int mf = 0; mf < 4; ++mf) B0[mf] = *(const half8*)(zr + (mf * 64 + lane) * 8);
#pragma unroll
        for (int mf = 0; mf < 4; ++mf) B1[mf] = *(const half8*)(zr + ((4 + mf) * 64 + lane) * 8);

        // acc starts at x: MFMA C-in accumulates, epilogue add eliminated
        float4v acc[4][4];
#pragma unroll
        for (int f = 0; f < 4; ++f)
#pragma unroll
            for (int mf = 0; mf < 4; ++mf) acc[f][mf] = xr[f][mf];

#pragma unroll
        for (int ks = 0; ks < 16; ++ks) {
            half8* Ac = ((ks & 3) == 0) ? A0 : ((ks & 3) == 1) ? A1 : ((ks & 3) == 2) ? A2 : A3;
            half8* Bc = (ks & 1) ? B1 : B0;
#pragma unroll
            for (int f = 0; f < 4; ++f)
#pragma unroll
                for (int mf = 0; mf < 4; ++mf)
                    acc[f][mf] = __builtin_amdgcn_mfma_f32_16x16x32_f16(Ac[f], Bc[mf], acc[f][mf], 0, 0, 0);
            // Refill the just-consumed A buffer with ks+4 (mod 16). W addresses
            // are iteration-independent, so at ks=12..15 this prefetches the
            // NEXT iteration's ks=0..3 across the barrier.
            {
                int ka = (ks + 4) & 15;
#pragma unroll
                for (int f = 0; f < 4; ++f) Ac[f] = Wv[ka * 2048 + f * 64];
            }
            // Refill B with ks+2 from the SAME z buffer (cannot cross the
            // barrier: the other buffer is being written by other waves).
            if (ks < 14) {
#pragma unroll
                for (int mf = 0; mf < 4; ++mf)
                    Bc[mf] = *(const half8*)(zr + (((ks + 2) * 4 + mf) * 64 + lane) * 8);
            }
        }

        if (it < NITER - 2) {
            // z_{k+1} = tanh(acc) -> other z buffer; no barrier needed before
            // the write (readers are on zsh[p], we write zsh[p^1]).
            _Float16* zw = &zsh[p ^ 1][0];
#pragma unroll
            for (int f = 0; f < 4; ++f) {
                int n = (nf0 + f) * 16 + quad * 4;
#pragma unroll
                for (int mf = 0; mf < 4; ++mf) {
                    int m = mf * 16 + l15;
                    half4v h;
#pragma unroll
                    for (int j = 0; j < 4; ++j) h[j] = (_Float16)fast_tanh(acc[f][mf][j]);
                    *(half4v*)(zw + zaddr(m, n)) = h;
                }
            }
            __syncthreads();   // single barrier per iteration
            p ^= 1;
        } else {
            // final iteration: store z50 straight from registers (fp32, nt)
#pragma unroll
            for (int f = 0; f < 4; ++f) {
                int n = (nf0 + f) * 16 + quad * 4;
#pragma unroll
                for (int mf = 0; mf < 4; ++mf) {
                    float4v v;
#pragma unroll
                    for (int j = 0; j < 4; ++j) v[j] = fast_tanh(acc[f][mf][j]);
                    float4v* op = (float4v*)(out + (size_t)(row_blk + mf * 16 + l15) * DDIM + n);
                    __builtin_nontemporal_store(v, op);
                }
            }
        }
    }
}

extern "C" void kernel_launch(void* const* d_in, const int* in_sizes, int n_in,
                              void* d_out, int out_size, void* d_ws, size_t ws_size,
                              hipStream_t stream) {
    const float* x = (const float*)d_in[0];   // [65536, 512] fp32
    const float* W = (const float*)d_in[1];   // [512, 512] fp32
    _Float16* Wpk = (_Float16*)d_ws;          // 512 KB packed f16 W
    float* out = (float*)d_out;

    wpack_kernel<<<128, 256, 0, stream>>>(W, Wpk);
    fixpoint_kernel<<<65536 / MTILE, 512, 0, stream>>>(x, Wpk, out);
}